// Round 1
// baseline (1084.069 us; speedup 1.0000x reference)
//
#include <hip/hip_runtime.h>
#include <cstdint>
#include <cstddef>

// Problem constants (from reference setup_inputs)
constexpr int P  = 200000;   // points
constexpr int C  = 256;      // clicks
constexpr int NC = 200;      // classes
#define DICE_TH 0.4f
#define CLS_TH  0.5f
#define LN_EPS  1e-5f

// gram split-K config: KC * NCHUNK == P
constexpr int KC = 1600;
constexpr int NCHUNK = 125;

// workspace byte offsets (total < 700 KB)
constexpr size_t WS_G       = 0;        // 256*256*4 = 262144
constexpr size_t WS_S       = 262144;   // 256*4
constexpr size_t WS_PROW    = 263168;   // 256*200*4 = 204800
constexpr size_t WS_PT      = 467968;   // 200*256*4 = 204800
constexpr size_t WS_COND    = 672768;   // 256*4*8 = 8192
constexpr size_t WS_MSTART  = 680960;   // 257*4
constexpr size_t WS_MEMBERS = 682240;   // 256*4

// ---------------------------------------------------------------------------
// Kernel 1: G = M^T M  (fp32, 128x128 output tiles, split-K with atomicAdd)
// also accumulates column sums s[c] on diagonal tiles (each col covered once).
// ---------------------------------------------------------------------------
__global__ __launch_bounds__(256) void gram_kernel(const float* __restrict__ M,
                                                   float* __restrict__ G,
                                                   float* __restrict__ s) {
  __shared__ float As[16][128];
  __shared__ float Bs[16][128];
  const int ti = blockIdx.x >> 1;
  const int tj = blockIdx.x & 1;
  const int i0 = ti * 128, j0 = tj * 128;
  const bool diag = (ti == tj);
  const int tid = threadIdx.x;
  const int tx = tid & 15, ty = tid >> 4;   // 16x16 threads, 8x8 acc each
  const int o4 = tid & 63;                  // float4 column group for staging
  const int rbase = tid >> 6;               // wave id -> staging row offset
  const int k0 = blockIdx.y * KC;

  float acc[8][8];
#pragma unroll
  for (int r = 0; r < 8; ++r)
#pragma unroll
    for (int c = 0; c < 8; ++c) acc[r][c] = 0.f;
  float4 csum = make_float4(0.f, 0.f, 0.f, 0.f);

  const float4* Mv = reinterpret_cast<const float4*>(M);
  const int col4 = (o4 < 32) ? (i0 / 4 + o4) : (j0 / 4 + (o4 - 32));

  for (int step = 0; step < KC / 16; ++step) {
    const int k = k0 + step * 16;
    // stage 16 rows x 256 cols (both 128-slices), 4 float4 per thread, coalesced
#pragma unroll
    for (int it = 0; it < 4; ++it) {
      const int r = it * 4 + rbase;
      float4 v = Mv[(size_t)(k + r) * 64 + col4];
      if (o4 < 32) {
        *reinterpret_cast<float4*>(&As[r][o4 * 4]) = v;
        if (diag) { csum.x += v.x; csum.y += v.y; csum.z += v.z; csum.w += v.w; }
      } else {
        *reinterpret_cast<float4*>(&Bs[r][(o4 - 32) * 4]) = v;
      }
    }
    __syncthreads();
#pragma unroll
    for (int kk = 0; kk < 16; ++kk) {
      float4 a0 = *reinterpret_cast<const float4*>(&As[kk][ty * 8]);
      float4 a1 = *reinterpret_cast<const float4*>(&As[kk][ty * 8 + 4]);
      float4 b0 = *reinterpret_cast<const float4*>(&Bs[kk][tx * 8]);
      float4 b1 = *reinterpret_cast<const float4*>(&Bs[kk][tx * 8 + 4]);
      float a[8] = {a0.x, a0.y, a0.z, a0.w, a1.x, a1.y, a1.z, a1.w};
      float b[8] = {b0.x, b0.y, b0.z, b0.w, b1.x, b1.y, b1.z, b1.w};
#pragma unroll
      for (int r = 0; r < 8; ++r)
#pragma unroll
        for (int c = 0; c < 8; ++c) acc[r][c] = fmaf(a[r], b[c], acc[r][c]);
    }
    __syncthreads();
  }

#pragma unroll
  for (int r = 0; r < 8; ++r)
#pragma unroll
    for (int c = 0; c < 8; ++c)
      atomicAdd(&G[(size_t)(i0 + ty * 8 + r) * 256 + (j0 + tx * 8 + c)],
                acc[r][c]);

  if (diag && o4 < 32) {
    atomicAdd(&s[i0 + o4 * 4 + 0], csum.x);
    atomicAdd(&s[i0 + o4 * 4 + 1], csum.y);
    atomicAdd(&s[i0 + o4 * 4 + 2], csum.z);
    atomicAdd(&s[i0 + o4 * 4 + 3], csum.w);
  }
}

// ---------------------------------------------------------------------------
// Kernel 2: layernorm of cls_logits -> p (row-major) and pT (transposed)
// one wave per click
// ---------------------------------------------------------------------------
__global__ __launch_bounds__(64) void ln_kernel(const float* __restrict__ cls,
                                                float* __restrict__ p_row,
                                                float* __restrict__ pT) {
  const int c = blockIdx.x;
  const int t = threadIdx.x;
  const float* x = cls + (size_t)c * NC;
  float v0 = x[t];
  float v1 = x[t + 64];
  float v2 = (t < 72) ? x[t + 128] : 0.f;

  float sum = v0 + v1 + v2;
#pragma unroll
  for (int o = 32; o > 0; o >>= 1) sum += __shfl_xor(sum, o);
  const float mu = sum / (float)NC;

  float d0 = v0 - mu, d1 = v1 - mu, d2 = (t < 72) ? (v2 - mu) : 0.f;
  float sq = d0 * d0 + d1 * d1 + d2 * d2;
#pragma unroll
  for (int o = 32; o > 0; o >>= 1) sq += __shfl_xor(sq, o);
  const float var = sq / (float)NC;
  const float inv = 1.0f / sqrtf(var + LN_EPS);

  float p0 = d0 * inv, p1 = d1 * inv, p2 = d2 * inv;
  p_row[(size_t)c * NC + t] = p0;
  p_row[(size_t)c * NC + t + 64] = p1;
  pT[(size_t)t * C + c] = p0;
  pT[(size_t)(t + 64) * C + c] = p1;
  if (t < 72) {
    p_row[(size_t)c * NC + t + 128] = p2;
    pT[(size_t)(t + 128) * C + c] = p2;
  }
}

// ---------------------------------------------------------------------------
// Kernel 3: cond[i][j] = (dice > 0.4) && (sim > 0.5), packed as 4x u64 per row
// block i, thread j
// ---------------------------------------------------------------------------
__global__ __launch_bounds__(256) void cond_kernel(
    const float* __restrict__ G, const float* __restrict__ s,
    const float* __restrict__ p_row, const float* __restrict__ pT,
    unsigned long long* __restrict__ condW) {
  __shared__ float pi[NC];
  const int i = blockIdx.x;
  const int j = threadIdx.x;
  if (j < NC) pi[j] = p_row[(size_t)i * NC + j];
  __syncthreads();

  const float si = s[i];
  const float sj = s[j];
  const float g = G[(size_t)i * C + j];
  const float dice = 2.f * g / (si + sj);

  float acc = 0.f;
#pragma unroll 8
  for (int k = 0; k < NC; ++k) acc = fmaf(pi[k], pT[(size_t)k * C + j], acc);

  const bool cnd = (dice > DICE_TH) && (acc > CLS_TH);
  unsigned long long m = __ballot(cnd);
  if ((j & 63) == 0) condW[i * 4 + (j >> 6)] = m;
}

// ---------------------------------------------------------------------------
// Kernel 4: sequential greedy scan (exact reference semantics), single wave.
// Produces labels (float to out, plus member lists to ws) and group_valid.
// ---------------------------------------------------------------------------
__global__ __launch_bounds__(64) void scan_kernel(
    const unsigned long long* __restrict__ condW,
    float* __restrict__ out_labels, float* __restrict__ out_valid,
    int* __restrict__ mstart, int* __restrict__ members) {
  __shared__ unsigned long long cS[C * 4];
  __shared__ int cnt[C];
  __shared__ int ms[C + 1];
  const int t = threadIdx.x;

  for (int idx = t; idx < C * 4; idx += 64) cS[idx] = condW[idx];
  for (int idx = t; idx < C; idx += 64) cnt[idx] = 0;
  __syncthreads();

  unsigned long long asg[4] = {0ull, 0ull, 0ull, 0ull};
  int lab[4] = {-1, -1, -1, -1};   // lab[w] is label of column w*64 + t

#pragma unroll
  for (int w = 0; w < 4; ++w) {
    for (int b = 0; b < 64; ++b) {
      const int i = w * 64 + b;
      if (!((asg[w] >> b) & 1ull)) {   // leader i: take unassigned matches
#pragma unroll
        for (int w2 = 0; w2 < 4; ++w2) {
          unsigned long long tk = cS[i * 4 + w2] & ~asg[w2];
          asg[w2] |= tk;
          if ((tk >> t) & 1ull) lab[w2] = i;
        }
      }
    }
  }

  // counts per leader
#pragma unroll
  for (int w = 0; w < 4; ++w)
    if (lab[w] >= 0) atomicAdd(&cnt[lab[w]], 1);
  __syncthreads();

  if (t == 0) {
    ms[0] = 0;
    for (int c2 = 0; c2 < C; ++c2) ms[c2 + 1] = ms[c2] + cnt[c2];
  }
  __syncthreads();
  // cursor = ms[c]
  for (int idx = t; idx < C; idx += 64) cnt[idx] = ms[idx];
  __syncthreads();
#pragma unroll
  for (int w = 0; w < 4; ++w) {
    if (lab[w] >= 0) {
      int pos = atomicAdd(&cnt[lab[w]], 1);
      members[pos] = w * 64 + t;
    }
  }
  // outputs
#pragma unroll
  for (int w = 0; w < 4; ++w) {
    const int col = w * 64 + t;
    out_labels[col] = (float)lab[w];
    out_valid[col] = (ms[col + 1] > ms[col]) ? 1.0f : 0.0f;
  }
  for (int idx = t; idx < C + 1; idx += 64) mstart[idx] = ms[idx];
}

// ---------------------------------------------------------------------------
// Kernel 5: new_masks[p][c] = valid(c) ? max over members of M[p][j] : 0
// 8 rows per block staged in LDS
// ---------------------------------------------------------------------------
__global__ __launch_bounds__(256) void merge_masks_kernel(
    const float* __restrict__ M, const int* __restrict__ mstart,
    const int* __restrict__ members, float* __restrict__ out_masks) {
  __shared__ float rows[8 * 256];
  __shared__ int msS[C + 1];
  __shared__ int memS[C];
  const int tid = threadIdx.x;
  const size_t p0 = (size_t)blockIdx.x * 8;

  msS[tid] = mstart[tid];
  if (tid == 0) msS[C] = mstart[C];
  memS[tid] = members[tid];

  const float4* src = reinterpret_cast<const float4*>(M + p0 * 256);
#pragma unroll
  for (int it = 0; it < 2; ++it)
    reinterpret_cast<float4*>(rows)[it * 256 + tid] = src[it * 256 + tid];
  __syncthreads();

  const int st = msS[tid], en = msS[tid + 1];
  float mx[8];
  if (en > st) {
    const int m0 = memS[st];
#pragma unroll
    for (int r = 0; r < 8; ++r) mx[r] = rows[r * 256 + m0];
    for (int k = st + 1; k < en; ++k) {
      const int mm = memS[k];
#pragma unroll
      for (int r = 0; r < 8; ++r) mx[r] = fmaxf(mx[r], rows[r * 256 + mm]);
    }
  } else {
#pragma unroll
    for (int r = 0; r < 8; ++r) mx[r] = 0.f;
  }
#pragma unroll
  for (int r = 0; r < 8; ++r) out_masks[(p0 + r) * 256 + tid] = mx[r];
}

// ---------------------------------------------------------------------------
// Kernel 6: new_cls[c][k] = valid(c) ? max over members of cls[j][k] : 0
// ---------------------------------------------------------------------------
__global__ __launch_bounds__(256) void merge_cls_kernel(
    const float* __restrict__ cls, const int* __restrict__ mstart,
    const int* __restrict__ members, float* __restrict__ out_cls) {
  __shared__ int se[2];
  const int c = blockIdx.x;
  const int t = threadIdx.x;
  if (t < 2) se[t] = mstart[c + t];
  __syncthreads();
  const int st = se[0], en = se[1];
  if (t < NC) {
    float mx = 0.f;
    if (en > st) {
      mx = cls[(size_t)members[st] * NC + t];
      for (int k = st + 1; k < en; ++k)
        mx = fmaxf(mx, cls[(size_t)members[k] * NC + t]);
    }
    out_cls[(size_t)c * NC + t] = mx;
  }
}

// ---------------------------------------------------------------------------
extern "C" void kernel_launch(void* const* d_in, const int* in_sizes, int n_in,
                              void* d_out, int out_size, void* d_ws,
                              size_t ws_size, hipStream_t stream) {
  const float* M = (const float*)d_in[0];    // [P, C] fp32
  const float* cls = (const float*)d_in[1];  // [C, NC] fp32
  // d_in[2] (clicks_list) unused by the random_clicks=True path

  float* out = (float*)d_out;
  char* ws = (char*)d_ws;
  float* G = (float*)(ws + WS_G);
  float* s = (float*)(ws + WS_S);
  float* p_row = (float*)(ws + WS_PROW);
  float* pT = (float*)(ws + WS_PT);
  unsigned long long* condW = (unsigned long long*)(ws + WS_COND);
  int* mstart = (int*)(ws + WS_MSTART);
  int* members = (int*)(ws + WS_MEMBERS);

  // out layout: labels[256] | group_valid[256] | new_masks[P*256] | new_cls[256*200]
  float* out_labels = out;
  float* out_valid = out + 256;
  float* out_masks = out + 512;
  float* out_cls = out + 512 + (size_t)P * 256;

  // zero accumulators (G and s are contiguous at ws start)
  hipMemsetAsync(ws, 0, WS_S + 1024, stream);

  gram_kernel<<<dim3(4, NCHUNK), 256, 0, stream>>>(M, G, s);
  ln_kernel<<<C, 64, 0, stream>>>(cls, p_row, pT);
  cond_kernel<<<C, 256, 0, stream>>>(G, s, p_row, pT, condW);
  scan_kernel<<<1, 64, 0, stream>>>(condW, out_labels, out_valid, mstart,
                                    members);
  merge_masks_kernel<<<P / 8, 256, 0, stream>>>(M, mstart, members, out_masks);
  merge_cls_kernel<<<C, 256, 0, stream>>>(cls, mstart, members, out_cls);
}

// Round 2
// 454.575 us; speedup vs baseline: 2.3848x; 2.3848x over previous
//
#include <hip/hip_runtime.h>
#include <cstdint>
#include <cstddef>

// Problem constants (from reference setup_inputs)
constexpr int P  = 200000;   // points
constexpr int C  = 256;      // clicks
constexpr int NC = 200;      // classes
#define DICE_TH 0.4f
#define CLS_TH  0.5f
#define LN_EPS  1e-5f

// gram split-K config: KC * NCHUNK == P, KC % 32 == 0
constexpr int KC = 1600;
constexpr int NCHUNK = 125;

// workspace byte offsets (total < 700 KB)
constexpr size_t WS_G       = 0;        // 256*256*4 = 262144
constexpr size_t WS_S       = 262144;   // 256*4
constexpr size_t WS_PROW    = 263168;   // 256*200*4 = 204800
constexpr size_t WS_PT      = 467968;   // 200*256*4 = 204800
constexpr size_t WS_COND    = 672768;   // 256*4*8 = 8192
constexpr size_t WS_MSTART  = 680960;   // 257*4
constexpr size_t WS_MEMBERS = 682240;   // 256*4

typedef float floatx16 __attribute__((ext_vector_type(16)));
typedef __bf16 bf16x8 __attribute__((ext_vector_type(8)));
typedef unsigned short ushort8 __attribute__((ext_vector_type(8)));

__device__ __forceinline__ unsigned short f2bf(float f) {
  unsigned u = __builtin_bit_cast(unsigned, f);
  unsigned r = u + 0x7FFFu + ((u >> 16) & 1u);   // RNE
  return (unsigned short)(r >> 16);
}

// ---------------------------------------------------------------------------
// Kernel 1: G = M^T M via bf16 MFMA (fp32 accumulate), split-K atomicAdd.
// Symmetric: only tiles (0,0),(0,1),(1,1) computed; cond reads mirror for
// the (1,0) quadrant. Column sums s fused into diag-block staging (fp32).
// LDS layout: [col][k] bf16, row stride 40 (32+8 pad -> conflict-free b128).
// ---------------------------------------------------------------------------
constexpr int LDA = 40;

__global__ __launch_bounds__(256, 2) void gram_mfma_kernel(
    const float* __restrict__ M, float* __restrict__ G, float* __restrict__ s) {
  __shared__ unsigned short Abf[128 * LDA];
  __shared__ unsigned short Bbf[128 * LDA];

  const int type = blockIdx.x;              // 0:(0,0) 1:(0,128) 2:(128,128)
  const int i0 = (type == 2) ? 128 : 0;
  const int j0 = (type == 0) ? 0 : 128;
  const bool diag = (type != 1);
  const int tid = threadIdx.x;
  const int wv = tid >> 6, lane = tid & 63;
  const int c = tid & 127, h = tid >> 7;    // staging: column, k-half (16 ks)
  const int k0 = blockIdx.y * KC;

  floatx16 acc[4];
#pragma unroll
  for (int t = 0; t < 4; ++t)
#pragma unroll
    for (int r = 0; r < 16; ++r) acc[t][r] = 0.f;
  float ssum = 0.f;

  // MFMA frag addresses (lane-fixed parts)
  const int mrow = lane & 31;
  const int kgrp = (lane >> 5) * 8;

  for (int step = 0; step < KC / 32; ++step) {
    const int kb = k0 + step * 32 + h * 16;
    {
      // stage A slice: col i0+c, k = kb..kb+15
      const float* col = M + (size_t)kb * 256 + i0 + c;
      float v[16];
#pragma unroll
      for (int u = 0; u < 16; ++u) v[u] = col[(size_t)u * 256];
      if (diag) {
#pragma unroll
        for (int u = 0; u < 16; ++u) ssum += v[u];
      }
      ushort8 lo, hi;
#pragma unroll
      for (int u = 0; u < 8; ++u) { lo[u] = f2bf(v[u]); hi[u] = f2bf(v[u + 8]); }
      *reinterpret_cast<ushort8*>(&Abf[c * LDA + h * 16]) = lo;
      *reinterpret_cast<ushort8*>(&Abf[c * LDA + h * 16 + 8]) = hi;
    }
    if (!diag) {
      // stage B slice: col j0+c
      const float* col = M + (size_t)kb * 256 + j0 + c;
      float v[16];
#pragma unroll
      for (int u = 0; u < 16; ++u) v[u] = col[(size_t)u * 256];
      ushort8 lo, hi;
#pragma unroll
      for (int u = 0; u < 8; ++u) { lo[u] = f2bf(v[u]); hi[u] = f2bf(v[u + 8]); }
      *reinterpret_cast<ushort8*>(&Bbf[c * LDA + h * 16]) = lo;
      *reinterpret_cast<ushort8*>(&Bbf[c * LDA + h * 16 + 8]) = hi;
    }
    __syncthreads();

    const unsigned short* Bsrc = diag ? Abf : Bbf;
#pragma unroll
    for (int sub = 0; sub < 2; ++sub) {
      const int ko = sub * 16 + kgrp;
      bf16x8 a = __builtin_bit_cast(
          bf16x8, *reinterpret_cast<const ushort8*>(
                      &Abf[(32 * wv + mrow) * LDA + ko]));
#pragma unroll
      for (int t = 0; t < 4; ++t) {
        bf16x8 b = __builtin_bit_cast(
            bf16x8, *reinterpret_cast<const ushort8*>(
                        &Bsrc[(32 * t + mrow) * LDA + ko]));
        acc[t] = __builtin_amdgcn_mfma_f32_32x32x16_bf16(a, b, acc[t], 0, 0, 0);
      }
    }
    __syncthreads();
  }

  // epilogue: C/D layout col=lane&31, row=(r&3)+8*(r>>2)+4*(lane>>5)
#pragma unroll
  for (int t = 0; t < 4; ++t) {
    const int gc = j0 + 32 * t + (lane & 31);
#pragma unroll
    for (int r = 0; r < 16; ++r) {
      const int gr = i0 + 32 * wv + (r & 3) + 8 * (r >> 2) + 4 * (lane >> 5);
      atomicAdd(&G[(size_t)gr * 256 + gc], acc[t][r]);
    }
  }
  if (diag) atomicAdd(&s[i0 + c], ssum);
}

// ---------------------------------------------------------------------------
// Kernel 2: layernorm of cls_logits -> p (row-major) and pT (transposed)
// ---------------------------------------------------------------------------
__global__ __launch_bounds__(64) void ln_kernel(const float* __restrict__ cls,
                                                float* __restrict__ p_row,
                                                float* __restrict__ pT) {
  const int c = blockIdx.x;
  const int t = threadIdx.x;
  const float* x = cls + (size_t)c * NC;
  float v0 = x[t];
  float v1 = x[t + 64];
  float v2 = (t < 72) ? x[t + 128] : 0.f;

  float sum = v0 + v1 + v2;
#pragma unroll
  for (int o = 32; o > 0; o >>= 1) sum += __shfl_xor(sum, o);
  const float mu = sum / (float)NC;

  float d0 = v0 - mu, d1 = v1 - mu, d2 = (t < 72) ? (v2 - mu) : 0.f;
  float sq = d0 * d0 + d1 * d1 + d2 * d2;
#pragma unroll
  for (int o = 32; o > 0; o >>= 1) sq += __shfl_xor(sq, o);
  const float var = sq / (float)NC;
  const float inv = 1.0f / sqrtf(var + LN_EPS);

  float p0 = d0 * inv, p1 = d1 * inv, p2 = d2 * inv;
  p_row[(size_t)c * NC + t] = p0;
  p_row[(size_t)c * NC + t + 64] = p1;
  pT[(size_t)t * C + c] = p0;
  pT[(size_t)(t + 64) * C + c] = p1;
  if (t < 72) {
    p_row[(size_t)c * NC + t + 128] = p2;
    pT[(size_t)(t + 128) * C + c] = p2;
  }
}

// ---------------------------------------------------------------------------
// Kernel 3: cond[i][j] = (dice > 0.4) && (sim > 0.5), packed 4x u64 per row.
// G's (i>=128, j<128) quadrant was not written (symmetry) -> read mirror.
// ---------------------------------------------------------------------------
__global__ __launch_bounds__(256) void cond_kernel(
    const float* __restrict__ G, const float* __restrict__ s,
    const float* __restrict__ p_row, const float* __restrict__ pT,
    unsigned long long* __restrict__ condW) {
  __shared__ float pi[NC];
  const int i = blockIdx.x;
  const int j = threadIdx.x;
  if (j < NC) pi[j] = p_row[(size_t)i * NC + j];
  __syncthreads();

  const float si = s[i];
  const float sj = s[j];
  const float g = (i >= 128 && j < 128) ? G[(size_t)j * C + i]
                                        : G[(size_t)i * C + j];
  const float dice = 2.f * g / (si + sj);

  float acc = 0.f;
#pragma unroll 8
  for (int k = 0; k < NC; ++k) acc = fmaf(pi[k], pT[(size_t)k * C + j], acc);

  const bool cnd = (dice > DICE_TH) && (acc > CLS_TH);
  unsigned long long m = __ballot(cnd);
  if ((j & 63) == 0) condW[i * 4 + (j >> 6)] = m;
}

// ---------------------------------------------------------------------------
// Kernel 4: sequential greedy scan (exact reference semantics), single wave.
// ---------------------------------------------------------------------------
__global__ __launch_bounds__(64) void scan_kernel(
    const unsigned long long* __restrict__ condW,
    float* __restrict__ out_labels, float* __restrict__ out_valid,
    int* __restrict__ mstart, int* __restrict__ members) {
  __shared__ unsigned long long cS[C * 4];
  __shared__ int cnt[C];
  __shared__ int ms[C + 1];
  const int t = threadIdx.x;

  for (int idx = t; idx < C * 4; idx += 64) cS[idx] = condW[idx];
  for (int idx = t; idx < C; idx += 64) cnt[idx] = 0;
  __syncthreads();

  unsigned long long asg[4] = {0ull, 0ull, 0ull, 0ull};
  int lab[4] = {-1, -1, -1, -1};   // lab[w] is label of column w*64 + t

#pragma unroll
  for (int w = 0; w < 4; ++w) {
    for (int b = 0; b < 64; ++b) {
      const int i = w * 64 + b;
      if (!((asg[w] >> b) & 1ull)) {   // leader i: take unassigned matches
#pragma unroll
        for (int w2 = 0; w2 < 4; ++w2) {
          unsigned long long tk = cS[i * 4 + w2] & ~asg[w2];
          asg[w2] |= tk;
          if ((tk >> t) & 1ull) lab[w2] = i;
        }
      }
    }
  }

  // counts per leader
#pragma unroll
  for (int w = 0; w < 4; ++w)
    if (lab[w] >= 0) atomicAdd(&cnt[lab[w]], 1);
  __syncthreads();

  if (t == 0) {
    ms[0] = 0;
    for (int c2 = 0; c2 < C; ++c2) ms[c2 + 1] = ms[c2] + cnt[c2];
  }
  __syncthreads();
  for (int idx = t; idx < C; idx += 64) cnt[idx] = ms[idx];
  __syncthreads();
#pragma unroll
  for (int w = 0; w < 4; ++w) {
    if (lab[w] >= 0) {
      int pos = atomicAdd(&cnt[lab[w]], 1);
      members[pos] = w * 64 + t;
    }
  }
#pragma unroll
  for (int w = 0; w < 4; ++w) {
    const int col = w * 64 + t;
    out_labels[col] = (float)lab[w];
    out_valid[col] = (ms[col + 1] > ms[col]) ? 1.0f : 0.0f;
  }
  for (int idx = t; idx < C + 1; idx += 64) mstart[idx] = ms[idx];
}

// ---------------------------------------------------------------------------
// Kernel 5: new_masks[p][c] = valid(c) ? max over members of M[p][j] : 0
// ---------------------------------------------------------------------------
__global__ __launch_bounds__(256) void merge_masks_kernel(
    const float* __restrict__ M, const int* __restrict__ mstart,
    const int* __restrict__ members, float* __restrict__ out_masks) {
  __shared__ float rows[8 * 256];
  __shared__ int msS[C + 1];
  __shared__ int memS[C];
  const int tid = threadIdx.x;
  const size_t p0 = (size_t)blockIdx.x * 8;

  msS[tid] = mstart[tid];
  if (tid == 0) msS[C] = mstart[C];
  memS[tid] = members[tid];

  const float4* src = reinterpret_cast<const float4*>(M + p0 * 256);
#pragma unroll
  for (int it = 0; it < 2; ++it)
    reinterpret_cast<float4*>(rows)[it * 256 + tid] = src[it * 256 + tid];
  __syncthreads();

  const int st = msS[tid], en = msS[tid + 1];
  float mx[8];
  if (en > st) {
    const int m0 = memS[st];
#pragma unroll
    for (int r = 0; r < 8; ++r) mx[r] = rows[r * 256 + m0];
    for (int k = st + 1; k < en; ++k) {
      const int mm = memS[k];
#pragma unroll
      for (int r = 0; r < 8; ++r) mx[r] = fmaxf(mx[r], rows[r * 256 + mm]);
    }
  } else {
#pragma unroll
    for (int r = 0; r < 8; ++r) mx[r] = 0.f;
  }
#pragma unroll
  for (int r = 0; r < 8; ++r) out_masks[(p0 + r) * 256 + tid] = mx[r];
}

// ---------------------------------------------------------------------------
// Kernel 6: new_cls[c][k] = valid(c) ? max over members of cls[j][k] : 0
// ---------------------------------------------------------------------------
__global__ __launch_bounds__(256) void merge_cls_kernel(
    const float* __restrict__ cls, const int* __restrict__ mstart,
    const int* __restrict__ members, float* __restrict__ out_cls) {
  __shared__ int se[2];
  const int c = blockIdx.x;
  const int t = threadIdx.x;
  if (t < 2) se[t] = mstart[c + t];
  __syncthreads();
  const int st = se[0], en = se[1];
  if (t < NC) {
    float mx = 0.f;
    if (en > st) {
      mx = cls[(size_t)members[st] * NC + t];
      for (int k = st + 1; k < en; ++k)
        mx = fmaxf(mx, cls[(size_t)members[k] * NC + t]);
    }
    out_cls[(size_t)c * NC + t] = mx;
  }
}

// ---------------------------------------------------------------------------
extern "C" void kernel_launch(void* const* d_in, const int* in_sizes, int n_in,
                              void* d_out, int out_size, void* d_ws,
                              size_t ws_size, hipStream_t stream) {
  const float* M = (const float*)d_in[0];    // [P, C] fp32
  const float* cls = (const float*)d_in[1];  // [C, NC] fp32

  float* out = (float*)d_out;
  char* ws = (char*)d_ws;
  float* G = (float*)(ws + WS_G);
  float* s = (float*)(ws + WS_S);
  float* p_row = (float*)(ws + WS_PROW);
  float* pT = (float*)(ws + WS_PT);
  unsigned long long* condW = (unsigned long long*)(ws + WS_COND);
  int* mstart = (int*)(ws + WS_MSTART);
  int* members = (int*)(ws + WS_MEMBERS);

  float* out_labels = out;
  float* out_valid = out + 256;
  float* out_masks = out + 512;
  float* out_cls = out + 512 + (size_t)P * 256;

  // zero accumulators (G and s are contiguous at ws start)
  hipMemsetAsync(ws, 0, WS_S + 1024, stream);

  gram_mfma_kernel<<<dim3(3, NCHUNK), 256, 0, stream>>>(M, G, s);
  ln_kernel<<<C, 64, 0, stream>>>(cls, p_row, pT);
  cond_kernel<<<C, 256, 0, stream>>>(G, s, p_row, pT, condW);
  scan_kernel<<<1, 64, 0, stream>>>(condW, out_labels, out_valid, mstart,
                                    members);
  merge_masks_kernel<<<P / 8, 256, 0, stream>>>(M, mstart, members, out_masks);
  merge_cls_kernel<<<C, 256, 0, stream>>>(cls, mstart, members, out_cls);
}